// Round 1
// baseline (945.289 us; speedup 1.0000x reference)
//
#include <hip/hip_runtime.h>

#define NPIX 36864   // 192*192

// ---------------------------------------------------------------- layer-1 1x1 (K=3)
__global__ __launch_bounds__(256) void l1_kernel(
    const float* __restrict__ p, const float* __restrict__ w,
    const float* __restrict__ b, float* __restrict__ out)
{
    int px = blockIdx.x * 256 + threadIdx.x;
    int c  = blockIdx.y;
    float acc = b[c];
    acc += w[c*3+0] * p[0*NPIX + px];
    acc += w[c*3+1] * p[1*NPIX + px];
    acc += w[c*3+2] * p[2*NPIX + px];
    out[(size_t)c * NPIX + px] = fmaxf(acc, 0.f);
}

// ---------------------------------------------------------------- fp32 tiled GEMM
// C[M][N] = relu?(A[M][K] * B[K][N] + bias[M]);  M%64==0, K%16==0, N%64==0
template<bool RELU>
__global__ __launch_bounds__(256) void gemm_bias(
    const float* __restrict__ A, const float* __restrict__ B,
    const float* __restrict__ bias, float* __restrict__ C,
    int M, int K, int N)
{
    __shared__ float As[16][64];   // transposed: As[k][m]
    __shared__ float Bs[16][64];
    const int tid = threadIdx.x;
    const int tx = tid & 15, ty = tid >> 4;
    const int row0 = blockIdx.y * 64, col0 = blockIdx.x * 64;
    const int a_m = tid >> 2, a_k = (tid & 3) * 4;
    const int b_k = tid >> 4, b_n = (tid & 15) * 4;
    float acc[4][4] = {};
    for (int k0 = 0; k0 < K; k0 += 16) {
        float4 av = *reinterpret_cast<const float4*>(&A[(size_t)(row0 + a_m) * K + k0 + a_k]);
        As[a_k+0][a_m] = av.x; As[a_k+1][a_m] = av.y;
        As[a_k+2][a_m] = av.z; As[a_k+3][a_m] = av.w;
        *reinterpret_cast<float4*>(&Bs[b_k][b_n]) =
            *reinterpret_cast<const float4*>(&B[(size_t)(k0 + b_k) * N + col0 + b_n]);
        __syncthreads();
        #pragma unroll
        for (int kk = 0; kk < 16; ++kk) {
            float4 a4 = *reinterpret_cast<const float4*>(&As[kk][ty*4]);
            float4 b4 = *reinterpret_cast<const float4*>(&Bs[kk][tx*4]);
            float ar[4] = {a4.x, a4.y, a4.z, a4.w};
            float br[4] = {b4.x, b4.y, b4.z, b4.w};
            #pragma unroll
            for (int i = 0; i < 4; ++i)
                #pragma unroll
                for (int j = 0; j < 4; ++j)
                    acc[i][j] += ar[i] * br[j];
        }
        __syncthreads();
    }
    #pragma unroll
    for (int i = 0; i < 4; ++i) {
        int m = row0 + ty*4 + i;
        float bv = bias[m];
        #pragma unroll
        for (int j = 0; j < 4; ++j) {
            float v = acc[i][j] + bv;
            if (RELU) v = fmaxf(v, 0.f);
            C[(size_t)m * N + col0 + tx*4 + j] = v;
        }
    }
}

// ---------------------------------------------------------------- direct 3x3 conv, pad=1
// in: [B][Cin][192][192], w: [Cout][Cin][3][3], out: [B][Cout][192][192]
template<int OCB>
__global__ __launch_bounds__(256) void conv3x3_kernel(
    const float* __restrict__ in, const float* __restrict__ w,
    const float* __restrict__ bias, float* __restrict__ out,
    int Cin, int Cout, int ocg_per_b, int relu)
{
    __shared__ float tile[10][34];           // 8x32 tile + 1-halo
    const int tid = threadIdx.x;
    const int lx = tid & 31, ly = tid >> 5;
    const int gx = blockIdx.x * 32 + lx;
    const int gy = blockIdx.y * 8 + ly;
    const int b   = blockIdx.z / ocg_per_b;
    const int oc0 = (blockIdx.z % ocg_per_b) * OCB;
    float acc[OCB];
    #pragma unroll
    for (int j = 0; j < OCB; ++j) acc[j] = bias[oc0 + j];
    for (int ic = 0; ic < Cin; ++ic) {
        const float* plane = in + (size_t)(b * Cin + ic) * NPIX;
        __syncthreads();
        for (int i = tid; i < 340; i += 256) {
            int ry = i / 34, rx = i % 34;
            int sy = blockIdx.y * 8 + ry - 1, sx = blockIdx.x * 32 + rx - 1;
            float v = 0.f;
            if (sy >= 0 && sy < 192 && sx >= 0 && sx < 192) v = plane[sy * 192 + sx];
            tile[ry][rx] = v;
        }
        __syncthreads();
        float patch[9];
        #pragma unroll
        for (int r = 0; r < 3; ++r)
            #pragma unroll
            for (int cc = 0; cc < 3; ++cc)
                patch[r*3+cc] = tile[ly + r][lx + cc];
        const float* wp = w + (size_t)(oc0 * Cin + ic) * 9;
        #pragma unroll
        for (int j = 0; j < OCB; ++j)
            #pragma unroll
            for (int t = 0; t < 9; ++t)
                acc[j] += patch[t] * wp[(size_t)j * Cin * 9 + t];
    }
    #pragma unroll
    for (int j = 0; j < OCB; ++j) {
        float v = acc[j];
        if (relu) v = fmaxf(v, 0.f);
        out[(size_t)(b * Cout + oc0 + j) * NPIX + gy * 192 + gx] = v;
    }
}

// ---------------------------------------------------------------- mean = sum_k h * softmax_k(dw)
__global__ __launch_bounds__(256) void mean_kernel(
    const float* __restrict__ x, const int* __restrict__ imy, const int* __restrict__ imx,
    const float* __restrict__ dw, float* __restrict__ mean)
{
    int px = blockIdx.x * 256 + threadIdx.x;
    int bc = blockIdx.y;           // b*64 + c
    int c  = bc & 63;
    int iy = imy[px], ix = imx[px];
    const float* xp = x + (size_t)bc * 9216;   // 96*96 plane
    float h[9], d[9];
    #pragma unroll
    for (int k = 0; k < 9; ++k) {
        int yy = iy + k/3 - 1, xx = ix + k%3 - 1;
        h[k] = (yy >= 0 && yy < 96 && xx >= 0 && xx < 96) ? xp[yy*96 + xx] : 0.f;
        d[k] = dw[(size_t)(c*9 + k) * NPIX + px];
    }
    float m = d[0];
    #pragma unroll
    for (int k = 1; k < 9; ++k) m = fmaxf(m, d[k]);
    float s = 0.f, a = 0.f;
    #pragma unroll
    for (int k = 0; k < 9; ++k) {
        float e = __expf(d[k] - m);
        s += e; a += e * h[k];
    }
    mean[(size_t)bc * NPIX + px] = a / s;
}

// ---------------------------------------------------------------- xa = sum_k h * softmax_k(bw)
__global__ __launch_bounds__(256) void xa_kernel(
    const float* __restrict__ x, const int* __restrict__ imy, const int* __restrict__ imx,
    const float* __restrict__ dw, const float* __restrict__ mean,
    const float* __restrict__ sigma, float* __restrict__ xa)
{
    int px = blockIdx.x * 256 + threadIdx.x;
    int bc = blockIdx.y;
    int c  = bc & 63;
    int b  = bc >> 6;
    int iy = imy[px], ix = imx[px];
    const float* xp = x + (size_t)bc * 9216;
    float mn = mean[(size_t)bc * NPIX + px];
    float sd = sigma[(size_t)(b*2 + 0) * NPIX + px];
    float sr = sigma[(size_t)(b*2 + 1) * NPIX + px];
    float h[9], bw[9];
    #pragma unroll
    for (int k = 0; k < 9; ++k) {
        int yy = iy + k/3 - 1, xx = ix + k%3 - 1;
        h[k] = (yy >= 0 && yy < 96 && xx >= 0 && xx < 96) ? xp[yy*96 + xx] : 0.f;
        float d = dw[(size_t)(c*9 + k) * NPIX + px];
        bw[k] = sd * d + sr * fabsf(h[k] - mn);
    }
    float m = bw[0];
    #pragma unroll
    for (int k = 1; k < 9; ++k) m = fmaxf(m, bw[k]);
    float s = 0.f, a = 0.f;
    #pragma unroll
    for (int k = 0; k < 9; ++k) {
        float e = __expf(bw[k] - m);
        s += e; a += e * h[k];
    }
    xa[(size_t)bc * NPIX + px] = a / s;
}

// ---------------------------------------------------------------- out[b,o] = sum_c xa[b,c]*pw[c,o]
__global__ __launch_bounds__(256) void einsum_kernel(
    const float* __restrict__ xa, const float* __restrict__ pw, float* __restrict__ out)
{
    int px = blockIdx.x * 256 + threadIdx.x;
    int b  = blockIdx.y;
    float a0 = 0.f, a1 = 0.f, a2 = 0.f;
    for (int c = 0; c < 64; ++c) {
        float v = xa[(size_t)(b*64 + c) * NPIX + px];
        a0 += v * pw[(size_t)(c*3 + 0) * NPIX + px];
        a1 += v * pw[(size_t)(c*3 + 1) * NPIX + px];
        a2 += v * pw[(size_t)(c*3 + 2) * NPIX + px];
    }
    out[(size_t)(b*3 + 0) * NPIX + px] = a0;
    out[(size_t)(b*3 + 1) * NPIX + px] = a1;
    out[(size_t)(b*3 + 2) * NPIX + px] = a2;
}

extern "C" void kernel_launch(void* const* d_in, const int* in_sizes, int n_in,
                              void* d_out, int out_size, void* d_ws, size_t ws_size,
                              hipStream_t stream)
{
    (void)in_sizes; (void)n_in; (void)out_size; (void)ws_size;
    const float* x      = (const float*)d_in[0];
    const float* pose   = (const float*)d_in[1];
    const int*   imy    = (const int*)d_in[2];
    const int*   imx    = (const int*)d_in[3];
    const float* sig_w1 = (const float*)d_in[4];
    const float* sig_b1 = (const float*)d_in[5];
    const float* sig_w2 = (const float*)d_in[6];
    const float* sig_b2 = (const float*)d_in[7];
    const float* sig_w3 = (const float*)d_in[8];
    const float* sig_b3 = (const float*)d_in[9];
    const float* dw_w1  = (const float*)d_in[10];
    const float* dw_b1  = (const float*)d_in[11];
    const float* dw_w2  = (const float*)d_in[12];
    const float* dw_b2  = (const float*)d_in[13];
    const float* dw_w3  = (const float*)d_in[14];
    const float* dw_b3  = (const float*)d_in[15];
    const float* pw_w1  = (const float*)d_in[16];
    const float* pw_b1  = (const float*)d_in[17];
    const float* pw_w2  = (const float*)d_in[18];
    const float* pw_b2  = (const float*)d_in[19];
    const float* pw_w3  = (const float*)d_in[20];
    const float* pw_b3  = (const float*)d_in[21];
    float* out = (float*)d_out;

    float* ws = (float*)d_ws;
    size_t off = 0;
    float* dwbuf = ws + off; off += (size_t)576 * NPIX;   // 85 MB, live until xa
    float* h1    = ws + off; off += (size_t)64  * NPIX;   // scratch for both chains
    float* h2    = ws + off; off += (size_t)256 * NPIX;   // scratch; later re-used as mean
    float* pwbuf = ws + off; off += (size_t)192 * NPIX;   // live until einsum
    float* s1    = ws + off; off += (size_t)128 * NPIX;   // sig hidden1; later re-used as xa
    float* s2    = ws + off; off += (size_t)128 * NPIX;   // sig hidden2
    float* sigma = ws + off; off += (size_t)4   * NPIX;
    float* meanb = h2;   // h2 dead after pw gemm
    float* xab   = s1;   // s1 dead after sigma computed

    dim3 blk(256);
    // dw chain: 3 -> 64 -> 256 -> 576 (per pixel 1x1)
    l1_kernel<<<dim3(144, 64), blk, 0, stream>>>(pose, dw_w1, dw_b1, h1);
    gemm_bias<true ><<<dim3(576, 4), blk, 0, stream>>>(dw_w2, h1, dw_b2, h2, 256, 64, NPIX);
    gemm_bias<false><<<dim3(576, 9), blk, 0, stream>>>(dw_w3, h2, dw_b3, dwbuf, 576, 256, NPIX);
    // pw chain: 3 -> 64 -> 256 -> 192
    l1_kernel<<<dim3(144, 64), blk, 0, stream>>>(pose, pw_w1, pw_b1, h1);
    gemm_bias<true ><<<dim3(576, 4), blk, 0, stream>>>(pw_w2, h1, pw_b2, h2, 256, 64, NPIX);
    gemm_bias<false><<<dim3(576, 3), blk, 0, stream>>>(pw_w3, h2, pw_b3, pwbuf, 192, 256, NPIX);
    // mean
    mean_kernel<<<dim3(144, 128), blk, 0, stream>>>(x, imy, imx, dwbuf, meanb);
    // sigma conv chain (3x3, pad 1): 64 -> 64 -> 64 -> 2
    conv3x3_kernel<16><<<dim3(6, 24, 8), blk, 0, stream>>>(meanb, sig_w1, sig_b1, s1, 64, 64, 4, 1);
    conv3x3_kernel<16><<<dim3(6, 24, 8), blk, 0, stream>>>(s1,    sig_w2, sig_b2, s2, 64, 64, 4, 1);
    conv3x3_kernel<2 ><<<dim3(6, 24, 2), blk, 0, stream>>>(s2,    sig_w3, sig_b3, sigma, 64, 2, 1, 0);
    // xa
    xa_kernel<<<dim3(144, 128), blk, 0, stream>>>(x, imy, imx, dwbuf, meanb, sigma, xab);
    // final contraction
    einsum_kernel<<<dim3(144, 2), blk, 0, stream>>>(xab, pwbuf, out);
}